// Round 8
// baseline (668.358 us; speedup 1.0000x reference)
//
#include <hip/hip_runtime.h>
#include <hip/hip_bf16.h>

#define BATCH 4
#define NPTS  8192
#define DIM   128
#define KNN   16
#define NROWS (BATCH * NPTS)   // 32768

#define SPLITS 16
#define RANGE  512             // candidates per split
#define TILE   256             // candidates per LDS tile (drain granularity)
#define DEPTH  32              // per-lane pending stack depth (per tile)
#define DEPTHP 34              // padded stride (odd*2 -> conflict-free writes)
#define NSUB   8               // limpass subsets

using u64  = unsigned long long;
using u32  = unsigned int;

__device__ __forceinline__ unsigned short f2bf(float f) {
    u32 u = __float_as_uint(f);
    u32 r = (u + 0x7FFFu + ((u >> 16) & 1u)) >> 16;  // RTNE
    return (unsigned short)r;
}
// monotone float -> uint mapping (handles negatives, e.g. self-distance ~ -1e-7)
__device__ __forceinline__ u32 fordkey(float f) {
    u32 u = __float_as_uint(f);
    return (u & 0x80000000u) ? ~u : (u | 0x80000000u);
}
// exact inverse of fordkey
__device__ __forceinline__ float invkey(u32 k) {
    u32 u = (k & 0x80000000u) ? (k & 0x7FFFFFFFu) : ~k;
    return __uint_as_float(u);
}

__device__ __forceinline__ void insert16(u64 key, u64* ks) {
    if (key < ks[15]) {
#pragma unroll
        for (int t = 0; t < 16; ++t) {
            u64 lo = key < ks[t] ? key : ks[t];
            u64 hi = key < ks[t] ? ks[t] : key;
            ks[t] = lo;
            key = hi;
        }
    }
}

// exact numpy fp32 op order: (sq_i + sq_j) - 2*((xx+yy)+zz)   [proven in R2]
__device__ __forceinline__ float pdist(float4 me, float4 c) {
    float dot = __fadd_rn(__fadd_rn(__fmul_rn(me.x, c.x), __fmul_rn(me.y, c.y)),
                          __fmul_rn(me.z, c.z));
    return __fsub_rn(__fadd_rn(me.w, c.w), __fmul_rn(2.0f, dot));
}

// ---------------------------------------------------------------- weights prep
__global__ __launch_bounds__(256) void prep_weights(const float* __restrict__ Wk,
                                                    const float* __restrict__ Wp2,
                                                    float* __restrict__ wk,
                                                    float* __restrict__ w2) {
    int tid = threadIdx.x;
    int c = tid & 127;
    const float* src = (tid < 128) ? Wk : Wp2;
    float s = 0.f;
    for (int d = 0; d < DIM; ++d) s += src[c * DIM + d];
    if (tid < 128) wk[c] = s;
    else           w2[c] = s;
}

// convert Wv / Wp2 / Wo to packed bf16 pairs, once (L2-resident afterwards)
__global__ __launch_bounds__(256) void conv_weights(const float* __restrict__ Wv,
                                                    const float* __restrict__ Wp2,
                                                    const float* __restrict__ Wo,
                                                    u32* __restrict__ Wb) {
    int i = blockIdx.x * 256 + threadIdx.x;   // 0 .. 3*8192-1
    int which = i >> 13, off = i & 8191;
    const float* W = (which == 0) ? Wv : (which == 1 ? Wp2 : Wo);
    float2 w = ((const float2*)W)[off];
    Wb[i] = (u32)f2bf(w.x) | ((u32)f2bf(w.y) << 16);
}

// ---------------------------------------------------------------- points prep
__global__ __launch_bounds__(256) void prep_points(const float* __restrict__ xyz,
                                                   const float* __restrict__ feat,
                                                   const float* __restrict__ wk,
                                                   float4* __restrict__ pts,
                                                   float* __restrict__ sK) {
    int lid = threadIdx.x & 63;
    int p = blockIdx.x * 4 + (threadIdx.x >> 6);
    float f_lo = feat[(size_t)p * DIM + lid];
    float f_hi = feat[(size_t)p * DIM + 64 + lid];
    float s = fmaf(f_lo, wk[lid], f_hi * wk[64 + lid]);
#pragma unroll
    for (int m = 32; m >= 1; m >>= 1) s += __shfl_xor(s, m);
    if (lid == 0) {
        float x = xyz[p * 3 + 0];
        float y = xyz[p * 3 + 1];
        float z = xyz[p * 3 + 2];
        float sq = __fadd_rn(__fadd_rn(__fmul_rn(x, x), __fmul_rn(y, y)), __fmul_rn(z, z));
        pts[p] = make_float4(x, y, z, sq);
        sK[p] = s;
    }
}

// ---------------------------------------------------------------- KNN limpass
// dlim[y][q] = 16th-smallest approx distance over candidates
// [y*256,(y+1)*256) of q's batch. Each is a valid upper bound on the global
// 16th-NN distance (>=16 candidates lie at/below it); partial takes the min
// of NSUB bounds (rank ~335 of 8192). Float-only chains (no indices).
__global__ __launch_bounds__(256) void knn_limpass(const float4* __restrict__ pts,
                                                   float* __restrict__ dlim) {
    __shared__ float4 tile[256];   // s-form: (x, y, z, -w/2)
    int y = blockIdx.y;
    int wavein = threadIdx.x >> 6, lane = threadIdx.x & 63;
    int q = blockIdx.x * 256 + wavein * 64 + lane;
    int b = q >> 13;   // uniform per block (256 | 8192)
    float4 me = pts[q];
    {
        float4 c = pts[b * NPTS + y * 256 + threadIdx.x];
        tile[threadIdx.x] = make_float4(c.x, c.y, c.z, -0.5f * c.w);
    }
    __syncthreads();
    float ks[16];
#pragma unroll
    for (int t = 0; t < 16; ++t) ks[t] = INFINITY;
    for (int jj = 0; jj < 256; ++jj) {
        float4 c = tile[jj];
        float s = fmaf(me.x, c.x, fmaf(me.y, c.y, fmaf(me.z, c.z, c.w)));
        float d = fmaf(-2.0f, s, me.w);
        if (d < ks[15]) {
#pragma unroll
            for (int t = 0; t < 16; ++t) {
                float lo = fminf(d, ks[t]);
                float hi = fmaxf(d, ks[t]);
                ks[t] = lo;
                d = hi;
            }
        }
    }
    dlim[(size_t)y * NROWS + q] = ks[15];
}

// ---------------------------------------------------------------- KNN partial
// grid (128, SPLITS); split r covers [r*RANGE,(r+1)*RANGE). Chains are
// sentinel-seeded at d_sent = T + 2e-4 (T = min of NSUB limpass bounds):
// >=16 candidates exist at/below d_sent, so the split union covers the
// global top-16. Scan is BRANCHLESS: unconditional ds_write_b16 of the
// candidate idx at slot=min(cnt,DEPTH-1), cnt += predicate — slots[0..cnt)
// are exactly the admits. Overflow (cnt>=DEPTH, P~1e-8) => that lane
// rescans the tile with exact direct inserts (correct fallback). Drains
// recompute the exact __f*_rn distance + exact u64 key, so final selection
// is bit-identical to numpy. Sentinel idx bits = 0xFFFF = empty marker.
__global__ __launch_bounds__(256) void knn_partial(const float4* __restrict__ pts,
                                                   const float* __restrict__ dlim,
                                                   unsigned short* __restrict__ part16) {
    __shared__ float4 tile[TILE];                    // 4 KB, s-form
    __shared__ unsigned short stk[4][64][DEPTHP];    // 17.4 KB, lane-major padded
    int r = blockIdx.y;
    int wavein = threadIdx.x >> 6, lane = threadIdx.x & 63;
    int q = blockIdx.x * 256 + wavein * 64 + lane;
    int b = q >> 13;   // uniform per block (256 | 8192)
    float4 me = pts[q];

    float T = dlim[q];
#pragma unroll
    for (int y = 1; y < NSUB; ++y) T = fminf(T, dlim[(size_t)y * NROWS + q]);
    float gate_d = T + 2.0e-4f;                       // sentinel level
    u64 sent = ((u64)fordkey(gate_d) << 32) | 0xFFFFFFFFull;
    u64 ks[16];
#pragma unroll
    for (int t = 0; t < 16; ++t) ks[t] = sent;
    float A = 0.5f * (me.w - gate_d) - 1.0e-4f;       // s >= A <=> d~ <= gate_d (+slop)
    unsigned short* mystk = stk[wavein][lane];

    for (int tb = 0; tb < RANGE / TILE; ++tb) {
        __syncthreads();
        int jb = r * RANGE + tb * TILE;
        {
            float4 c = pts[b * NPTS + jb + threadIdx.x];
            tile[threadIdx.x] = make_float4(c.x, c.y, c.z, -0.5f * c.w);
        }
        __syncthreads();

        int cnt = 0;
#pragma unroll 4
        for (int jj = 0; jj < TILE; ++jj) {
            float4 c = tile[jj];
            float s = fmaf(me.x, c.x, fmaf(me.y, c.y, fmaf(me.z, c.z, c.w)));
            int slot = cnt < (DEPTH - 1) ? cnt : (DEPTH - 1);
            mystk[slot] = (unsigned short)jj;          // unconditional (branchless)
            cnt += (s >= A) ? 1 : 0;
        }
        bool over = (cnt >= DEPTH);                    // trailing writes corrupt slot31
        int dn = over ? 0 : cnt;
        // drain pending (per-wave, exec-masked to max(dn) iterations)
        for (int i = 0; i < dn; ++i) {
            int jj = mystk[i];
            float4 c = tile[jj];
            float4 cc = make_float4(c.x, c.y, c.z, -2.0f * c.w);  // exact w recovery
            float d = pdist(me, cc);
            u64 key = ((u64)fordkey(d) << 32) | (u32)(jb + jj);
            insert16(key, ks);
        }
        if (__any(over)) {                             // ~never: exact re-scan
            if (over) {
                for (int jj = 0; jj < TILE; ++jj) {
                    float4 c = tile[jj];
                    float s = fmaf(me.x, c.x, fmaf(me.y, c.y, fmaf(me.z, c.z, c.w)));
                    if (s >= A) {
                        float4 cc = make_float4(c.x, c.y, c.z, -2.0f * c.w);
                        float d = pdist(me, cc);
                        u64 key = ((u64)fordkey(d) << 32) | (u32)(jb + jj);
                        insert16(key, ks);
                    }
                }
            }
        }
        float nl = invkey((u32)(ks[15] >> 32)) + 1.0e-4f;  // exact-vs-approx slop
        gate_d = (nl < gate_d) ? nl : gate_d;              // monotone ratchet
        A = 0.5f * (me.w - gate_d) - 1.0e-4f;
    }
#pragma unroll
    for (int t = 0; t < 16; ++t)
        part16[(size_t)(r * 16 + t) * NROWS + q] = (unsigned short)(ks[t] & 0xFFFFu);
}

// ---------------------------------------------------------------- KNN merge
// Re-derives exact u64 keys from pts (identical fp32 formula) -> ordering
// identical to a full u64 merge. 0xFFFF = empty/sentinel slot.
__global__ __launch_bounds__(256) void knn_merge(const float4* __restrict__ pts,
                                                 const unsigned short* __restrict__ part16,
                                                 int* __restrict__ idx16) {
    int q = blockIdx.x * 256 + threadIdx.x;
    int b = q >> 13;
    float4 me = pts[q];
    u64 ks[16];
#pragma unroll
    for (int t = 0; t < 16; ++t) ks[t] = ~0ull;
    for (int i = 0; i < SPLITS * 16; ++i) {
        unsigned short id = part16[(size_t)i * NROWS + q];
        if (id != 0xFFFF) {
            float d = pdist(me, pts[b * NPTS + id]);
            u64 key = ((u64)fordkey(d) << 32) | (u32)id;
            insert16(key, ks);
        }
    }
#pragma unroll
    for (int t = 0; t < 16; ++t)
        idx16[q * KNN + t] = (int)(ks[t] & 0xFFFFFFFFu);
}

// ---------------------------------------------------------------- GEMM 32-row
// X fp32, W pre-packed bf16 pairs (global, staged to LDS), accum fp32.
// MODE 0: Vf   = X @ Wv + bv                      -> fp32
// MODE 1: T1   = X @ Wp2 + bp2 + add(vagg)        -> fp32
// MODE 2: out  = featb + gamma*(X @ Wo + bo)      -> fp32
template <int MODE>
__global__ __launch_bounds__(256) void gemm32(const float* __restrict__ X,
                                              const u32* __restrict__ Wb,
                                              const float* __restrict__ bias,
                                              const float* __restrict__ add,
                                              const float* __restrict__ featb,
                                              const float* __restrict__ gammap,
                                              float* __restrict__ outv) {
    __shared__ u32 Ws[DIM * DIM / 2];   // 32 KB packed bf16 pairs, [c][d/2]
    __shared__ float Xs[8 * DIM];       // 4 KB
    __shared__ float bs[DIM];
    int tid = threadIdx.x;
    {
        const uint4* src = (const uint4*)Wb;
        uint4* dst = (uint4*)Ws;
        for (int i = tid; i < DIM * DIM / 8; i += 256) dst[i] = src[i];
    }
    if (tid < 128) bs[tid] = bias[tid];
    float gamma = 0.f;
    if (MODE == 2) gamma = *gammap;

    int rowBase = blockIdx.x * 32;
    int d4 = (tid & 31) * 4;
    int row = tid >> 5;  // 0..7

    for (int it = 0; it < 4; ++it) {
        int r0 = rowBase + it * 8;
        __syncthreads();
        ((float4*)Xs)[tid] = ((const float4*)(X + (size_t)r0 * DIM))[tid];
        __syncthreads();

        float a0 = bs[d4], a1 = bs[d4 + 1], a2 = bs[d4 + 2], a3 = bs[d4 + 3];
        const float* xr = &Xs[row * DIM];
#pragma unroll 8
        for (int c = 0; c < DIM; ++c) {
            float x = xr[c];
            uint2 w = *(const uint2*)&Ws[c * (DIM / 2) + (d4 >> 1)];
            a0 = fmaf(x, __uint_as_float(w.x << 16), a0);
            a1 = fmaf(x, __uint_as_float(w.x & 0xFFFF0000u), a1);
            a2 = fmaf(x, __uint_as_float(w.y << 16), a2);
            a3 = fmaf(x, __uint_as_float(w.y & 0xFFFF0000u), a3);
        }
        size_t off = (size_t)(r0 + row) * DIM + d4;
        if (MODE == 1) {
            float4 ad = *(const float4*)(add + off);
            a0 += ad.x; a1 += ad.y; a2 += ad.z; a3 += ad.w;
        }
        if (MODE == 2) {
            float4 fb = *(const float4*)(featb + off);
            a0 = fmaf(gamma, a0, fb.x);
            a1 = fmaf(gamma, a1, fb.y);
            a2 = fmaf(gamma, a2, fb.z);
            a3 = fmaf(gamma, a3, fb.w);
        }
        *(float4*)(outv + off) = make_float4(a0, a1, a2, a3);
    }
}

// ---------------------------------------------------------------- stage C
__global__ __launch_bounds__(256) void stage_c(const float4* __restrict__ pts,
                                               const int* __restrict__ idx16,
                                               const float* __restrict__ sK,
                                               const float* __restrict__ w2,
                                               const float* __restrict__ Wp1,
                                               const float* __restrict__ bp1,
                                               const float* __restrict__ Vf,
                                               float* __restrict__ vagg,
                                               float* __restrict__ hbar) {
    __shared__ float hs[4][KNN * DIM];  // 32 KB
    int wavein = threadIdx.x >> 6;
    int lid = threadIdx.x & 63;
    int p = blockIdx.x * 4 + wavein;
    int b = p >> 13;
    float4 me = pts[p];

    float wx_lo = Wp1[lid],        wx_hi = Wp1[64 + lid];
    float wy_lo = Wp1[128 + lid],  wy_hi = Wp1[192 + lid];
    float wz_lo = Wp1[256 + lid],  wz_hi = Wp1[320 + lid];
    float bl    = bp1[lid],        bh    = bp1[64 + lid];
    float w2l   = w2[lid],         w2h   = w2[64 + lid];

    int myidx = idx16[p * KNN + (lid & 15)];
    float* h = hs[wavein];
    float sc = -INFINITY;

    for (int k = 0; k < KNN; ++k) {
        int j = __shfl(myidx, k);
        int g = b * NPTS + j;
        float4 nb = pts[g];
        float rx = me.x - nb.x, ry = me.y - nb.y, rz = me.z - nb.z;
        float h_lo = fmaxf(0.f, fmaf(rx, wx_lo, fmaf(ry, wy_lo, fmaf(rz, wz_lo, bl))));
        float h_hi = fmaxf(0.f, fmaf(rx, wx_hi, fmaf(ry, wy_hi, fmaf(rz, wz_hi, bh))));
        h[k * DIM + lid] = h_lo;
        h[k * DIM + 64 + lid] = h_hi;
        float s = fmaf(h_lo, w2l, h_hi * w2h);
#pragma unroll
        for (int m = 32; m >= 1; m >>= 1) s += __shfl_xor(s, m);
        float score = s - sK[g];
        if (lid == k) sc = score;
    }
    float mx = sc;
#pragma unroll
    for (int m = 8; m >= 1; m >>= 1) mx = fmaxf(mx, __shfl_xor(mx, m));
    float e = (lid < 16) ? __expf(sc - mx) : 0.f;
    float ssum = e;
#pragma unroll
    for (int m = 8; m >= 1; m >>= 1) ssum += __shfl_xor(ssum, m);
    float a = e / ssum;

    float acc_lo = 0.f, acc_hi = 0.f, hb_lo = 0.f, hb_hi = 0.f;
    for (int k = 0; k < KNN; ++k) {
        float ak = __shfl(a, k);
        int j = __shfl(myidx, k);
        size_t g = (size_t)(b * NPTS + j) * DIM;
        acc_lo = fmaf(ak, Vf[g + lid], acc_lo);
        acc_hi = fmaf(ak, Vf[g + 64 + lid], acc_hi);
        hb_lo = fmaf(ak, h[k * DIM + lid], hb_lo);
        hb_hi = fmaf(ak, h[k * DIM + 64 + lid], hb_hi);
    }
    size_t o = (size_t)p * DIM;
    vagg[o + lid] = acc_lo;
    vagg[o + 64 + lid] = acc_hi;
    hbar[o + lid] = hb_lo;
    hbar[o + 64 + lid] = hb_hi;
}

// ---------------------------------------------------------------- launcher
extern "C" void kernel_launch(void* const* d_in, const int* in_sizes, int n_in,
                              void* d_out, int out_size, void* d_ws, size_t ws_size,
                              hipStream_t stream) {
    const float* xyz   = (const float*)d_in[0];
    const float* feat  = (const float*)d_in[1];
    // d_in[2]=Wq, d_in[3]=bq, d_in[5]=bk: provably irrelevant (softmax shift-invariance)
    const float* Wk    = (const float*)d_in[4];
    const float* Wv    = (const float*)d_in[6];
    const float* bv    = (const float*)d_in[7];
    const float* Wp1   = (const float*)d_in[8];
    const float* bp1   = (const float*)d_in[9];
    const float* Wp2   = (const float*)d_in[10];
    const float* bp2   = (const float*)d_in[11];
    const float* Wo    = (const float*)d_in[12];
    const float* bo    = (const float*)d_in[13];
    const float* gamma = (const float*)d_in[14];
    float* out = (float*)d_out;

    char* ws = (char*)d_ws;
    const size_t KB = 1024, MB = 1024 * 1024;
    float*  wk    = (float*)(ws + 0);                // 512 B
    float*  w2    = (float*)(ws + 4 * KB);           // 512 B
    float4* pts   = (float4*)(ws + 16 * KB);         // 512 KB
    float*  sKv   = (float*)(ws + 544 * KB);         // 128 KB
    u32*    Wb    = (u32*)(ws + 688 * KB);           // 96 KB (Wv|Wp2|Wo bf16)
    float*  dlim  = (float*)(ws + 1 * MB);           // 1 MB (NSUB x NROWS)
    unsigned short* part16 = (unsigned short*)(ws + 5 * MB); // 16 MB, dead after merge
    float*  vagg  = (float*)(ws + 5 * MB);           // 16 MB, aliases dead part16
    float*  hbarp = (float*)(ws + 21 * MB);          // 16 MB
    int*    idx16 = (int*)(ws + 37 * MB);            // 2 MB
    float*  Vf    = (float*)(ws + 39 * MB);          // 16 MB, dead after stage_c
    float*  T1    = (float*)(ws + 39 * MB);          // aliases Vf  (total 55 MB)

    prep_weights<<<1, 256, 0, stream>>>(Wk, Wp2, wk, w2);
    conv_weights<<<96, 256, 0, stream>>>(Wv, Wp2, Wo, Wb);
    prep_points<<<NROWS / 4, 256, 0, stream>>>(xyz, feat, wk, pts, sKv);
    gemm32<0><<<1024, 256, 0, stream>>>(feat, Wb, bv, nullptr, nullptr, nullptr, Vf);
    knn_limpass<<<dim3(NROWS / 256, NSUB), 256, 0, stream>>>(pts, dlim);
    knn_partial<<<dim3(NROWS / 256, SPLITS), 256, 0, stream>>>(pts, dlim, part16);
    knn_merge<<<NROWS / 256, 256, 0, stream>>>(pts, part16, idx16);
    stage_c<<<NROWS / 4, 256, 0, stream>>>(pts, idx16, sKv, w2, Wp1, bp1, Vf, vagg, hbarp);
    gemm32<1><<<1024, 256, 0, stream>>>(hbarp, Wb + 8192, bp2, vagg, nullptr, nullptr, T1);
    gemm32<2><<<1024, 256, 0, stream>>>(T1, Wb + 16384, bo, nullptr, feat, gamma, out);
}

// Round 9
// 557.230 us; speedup vs baseline: 1.1994x; 1.1994x over previous
//
#include <hip/hip_runtime.h>
#include <hip/hip_bf16.h>

#define BATCH 4
#define NPTS  8192
#define DIM   128
#define KNN   16
#define NROWS (BATCH * NPTS)   // 32768

#define SPLITS 16
#define RANGE  512             // candidates per split
#define TILE   256             // candidates per LDS tile (drain granularity)
#define DEPTH  32              // per-lane pending stack depth (per tile)
#define DEPTHP 34              // padded stride (odd*2 -> conflict-free writes)
#define NSUB   8               // limpass subsets

using u64  = unsigned long long;
using u32  = unsigned int;

__device__ __forceinline__ unsigned short f2bf(float f) {
    u32 u = __float_as_uint(f);
    u32 r = (u + 0x7FFFu + ((u >> 16) & 1u)) >> 16;  // RTNE
    return (unsigned short)r;
}
// monotone float -> uint mapping (handles negatives, e.g. self-distance ~ -1e-7)
__device__ __forceinline__ u32 fordkey(float f) {
    u32 u = __float_as_uint(f);
    return (u & 0x80000000u) ? ~u : (u | 0x80000000u);
}
// exact inverse of fordkey
__device__ __forceinline__ float invkey(u32 k) {
    u32 u = (k & 0x80000000u) ? (k & 0x7FFFFFFFu) : ~k;
    return __uint_as_float(u);
}

__device__ __forceinline__ void insert16(u64 key, u64* ks) {
    if (key < ks[15]) {
#pragma unroll
        for (int t = 0; t < 16; ++t) {
            u64 lo = key < ks[t] ? key : ks[t];
            u64 hi = key < ks[t] ? ks[t] : key;
            ks[t] = lo;
            key = hi;
        }
    }
}

// exact numpy fp32 op order: (sq_i + sq_j) - 2*((xx+yy)+zz)   [proven in R2]
__device__ __forceinline__ float pdist(float4 me, float4 c) {
    float dot = __fadd_rn(__fadd_rn(__fmul_rn(me.x, c.x), __fmul_rn(me.y, c.y)),
                          __fmul_rn(me.z, c.z));
    return __fsub_rn(__fadd_rn(me.w, c.w), __fmul_rn(2.0f, dot));
}

// ---------------------------------------------------------------- weights prep
__global__ __launch_bounds__(256) void prep_weights(const float* __restrict__ Wk,
                                                    const float* __restrict__ Wp2,
                                                    float* __restrict__ wk,
                                                    float* __restrict__ w2) {
    int tid = threadIdx.x;
    int c = tid & 127;
    const float* src = (tid < 128) ? Wk : Wp2;
    float s = 0.f;
    for (int d = 0; d < DIM; ++d) s += src[c * DIM + d];
    if (tid < 128) wk[c] = s;
    else           w2[c] = s;
}

// convert Wv / Wp2 / Wo to packed bf16 pairs, once (L2-resident afterwards)
__global__ __launch_bounds__(256) void conv_weights(const float* __restrict__ Wv,
                                                    const float* __restrict__ Wp2,
                                                    const float* __restrict__ Wo,
                                                    u32* __restrict__ Wb) {
    int i = blockIdx.x * 256 + threadIdx.x;   // 0 .. 3*8192-1
    int which = i >> 13, off = i & 8191;
    const float* W = (which == 0) ? Wv : (which == 1 ? Wp2 : Wo);
    float2 w = ((const float2*)W)[off];
    Wb[i] = (u32)f2bf(w.x) | ((u32)f2bf(w.y) << 16);
}

// ---------------------------------------------------------------- points prep
__global__ __launch_bounds__(256) void prep_points(const float* __restrict__ xyz,
                                                   const float* __restrict__ feat,
                                                   const float* __restrict__ wk,
                                                   float4* __restrict__ pts,
                                                   float* __restrict__ sK) {
    int lid = threadIdx.x & 63;
    int p = blockIdx.x * 4 + (threadIdx.x >> 6);
    float f_lo = feat[(size_t)p * DIM + lid];
    float f_hi = feat[(size_t)p * DIM + 64 + lid];
    float s = fmaf(f_lo, wk[lid], f_hi * wk[64 + lid]);
#pragma unroll
    for (int m = 32; m >= 1; m >>= 1) s += __shfl_xor(s, m);
    if (lid == 0) {
        float x = xyz[p * 3 + 0];
        float y = xyz[p * 3 + 1];
        float z = xyz[p * 3 + 2];
        float sq = __fadd_rn(__fadd_rn(__fmul_rn(x, x), __fmul_rn(y, y)), __fmul_rn(z, z));
        pts[p] = make_float4(x, y, z, sq);
        sK[p] = s;
    }
}

// ---------------------------------------------------------------- KNN limpass
// dlim[y][q] = 16th-smallest approx distance over candidates
// [y*256,(y+1)*256) of q's batch (a valid upper bound on the global 16th-NN
// distance). Deferred-drain structure: 32-candidate warmup chain, then
// 32-candidate chunks (chunk <= DEPTH => no overflow path needed) with
// branchless stack push + per-lane drain.
__global__ __launch_bounds__(256) void knn_limpass(const float4* __restrict__ pts,
                                                   float* __restrict__ dlim) {
    __shared__ float4 tile[256];                   // 4 KB, s-form (x,y,z,-w/2)
    __shared__ unsigned short stk[4][64][DEPTHP];  // 17.4 KB
    int y = blockIdx.y;
    int wavein = threadIdx.x >> 6, lane = threadIdx.x & 63;
    int q = blockIdx.x * 256 + wavein * 64 + lane;
    int b = q >> 13;   // uniform per block (256 | 8192)
    float4 me = pts[q];
    {
        float4 c = pts[b * NPTS + y * 256 + threadIdx.x];
        tile[threadIdx.x] = make_float4(c.x, c.y, c.z, -0.5f * c.w);
    }
    __syncthreads();
    float ks[16];
#pragma unroll
    for (int t = 0; t < 16; ++t) ks[t] = INFINITY;
    unsigned short* mystk = stk[wavein][lane];

    // warmup: direct float-chain inserts over first 32 candidates
    for (int jj = 0; jj < 32; ++jj) {
        float4 c = tile[jj];
        float s = fmaf(me.x, c.x, fmaf(me.y, c.y, fmaf(me.z, c.z, c.w)));
        float d = fmaf(-2.0f, s, me.w);
        if (d < ks[15]) {
#pragma unroll
            for (int t = 0; t < 16; ++t) {
                float lo = fminf(d, ks[t]);
                float hi = fmaxf(d, ks[t]);
                ks[t] = lo;
                d = hi;
            }
        }
    }
    float lim = ks[15];
    // chunks of 32: branchless push + drain
    for (int c0 = 32; c0 < 256; c0 += 32) {
        int cnt = 0;
#pragma unroll
        for (int jj = c0; jj < c0 + 32; ++jj) {
            float4 c = tile[jj];
            float s = fmaf(me.x, c.x, fmaf(me.y, c.y, fmaf(me.z, c.z, c.w)));
            float d = fmaf(-2.0f, s, me.w);
            int slot = cnt < (DEPTH - 1) ? cnt : (DEPTH - 1);
            mystk[slot] = (unsigned short)jj;       // unconditional (branchless)
            cnt += (d < lim) ? 1 : 0;
        }
        for (int i = 0; i < cnt; ++i) {             // exec-masked to max(cnt)
            int jj = mystk[i];
            float4 c = tile[jj];
            float s = fmaf(me.x, c.x, fmaf(me.y, c.y, fmaf(me.z, c.z, c.w)));
            float d = fmaf(-2.0f, s, me.w);
            if (d < ks[15]) {
#pragma unroll
                for (int t = 0; t < 16; ++t) {
                    float lo = fminf(d, ks[t]);
                    float hi = fmaxf(d, ks[t]);
                    ks[t] = lo;
                    d = hi;
                }
            }
        }
        lim = ks[15];
    }
    dlim[(size_t)y * NROWS + q] = ks[15];
}

// ---------------------------------------------------------------- KNN partial
// grid (128, SPLITS); split r covers [r*RANGE,(r+1)*RANGE). Chains are
// sentinel-seeded at d_sent = T + 2e-4 (T = min of NSUB limpass bounds):
// >=16 candidates exist at/below d_sent, so the split union covers the
// global top-16. Branchless scan stack; overflow (cnt>=DEPTH, P~1e-8) =>
// exact rescan fallback. Drains recompute the exact __f*_rn distance +
// exact u64 key => final selection bit-identical to numpy.
// part16 is QUERY-MAJOR: part16[q*256 + r*16 + t]; idx 0xFFFF = empty.
__global__ __launch_bounds__(256) void knn_partial(const float4* __restrict__ pts,
                                                   const float* __restrict__ dlim,
                                                   unsigned short* __restrict__ part16) {
    __shared__ float4 tile[TILE];                    // 4 KB, s-form
    __shared__ unsigned short stk[4][64][DEPTHP];    // 17.4 KB
    int r = blockIdx.y;
    int wavein = threadIdx.x >> 6, lane = threadIdx.x & 63;
    int q = blockIdx.x * 256 + wavein * 64 + lane;
    int b = q >> 13;   // uniform per block (256 | 8192)
    float4 me = pts[q];

    float T = dlim[q];
#pragma unroll
    for (int y = 1; y < NSUB; ++y) T = fminf(T, dlim[(size_t)y * NROWS + q]);
    float gate_d = T + 2.0e-4f;                       // sentinel level
    u64 sent = ((u64)fordkey(gate_d) << 32) | 0xFFFFFFFFull;
    u64 ks[16];
#pragma unroll
    for (int t = 0; t < 16; ++t) ks[t] = sent;
    float A = 0.5f * (me.w - gate_d) - 1.0e-4f;       // s >= A <=> d~ <= gate_d (+slop)
    unsigned short* mystk = stk[wavein][lane];

    for (int tb = 0; tb < RANGE / TILE; ++tb) {
        __syncthreads();
        int jb = r * RANGE + tb * TILE;
        {
            float4 c = pts[b * NPTS + jb + threadIdx.x];
            tile[threadIdx.x] = make_float4(c.x, c.y, c.z, -0.5f * c.w);
        }
        __syncthreads();

        int cnt = 0;
#pragma unroll 4
        for (int jj = 0; jj < TILE; ++jj) {
            float4 c = tile[jj];
            float s = fmaf(me.x, c.x, fmaf(me.y, c.y, fmaf(me.z, c.z, c.w)));
            int slot = cnt < (DEPTH - 1) ? cnt : (DEPTH - 1);
            mystk[slot] = (unsigned short)jj;          // unconditional (branchless)
            cnt += (s >= A) ? 1 : 0;
        }
        bool over = (cnt >= DEPTH);                    // trailing writes corrupt slot31
        int dn = over ? 0 : cnt;
        for (int i = 0; i < dn; ++i) {                 // exec-masked to max(dn)
            int jj = mystk[i];
            float4 c = tile[jj];
            float4 cc = make_float4(c.x, c.y, c.z, -2.0f * c.w);  // exact w recovery
            float d = pdist(me, cc);
            u64 key = ((u64)fordkey(d) << 32) | (u32)(jb + jj);
            insert16(key, ks);
        }
        if (__any(over)) {                             // ~never: exact re-scan
            if (over) {
                for (int jj = 0; jj < TILE; ++jj) {
                    float4 c = tile[jj];
                    float s = fmaf(me.x, c.x, fmaf(me.y, c.y, fmaf(me.z, c.z, c.w)));
                    if (s >= A) {
                        float4 cc = make_float4(c.x, c.y, c.z, -2.0f * c.w);
                        float d = pdist(me, cc);
                        u64 key = ((u64)fordkey(d) << 32) | (u32)(jb + jj);
                        insert16(key, ks);
                    }
                }
            }
        }
        float nl = invkey((u32)(ks[15] >> 32)) + 1.0e-4f;  // exact-vs-approx slop
        gate_d = (nl < gate_d) ? nl : gate_d;              // monotone ratchet
        A = 0.5f * (me.w - gate_d) - 1.0e-4f;
    }
    u32* dst = (u32*)(part16 + (size_t)q * 256 + r * 16);
#pragma unroll
    for (int t = 0; t < 8; ++t)
        dst[t] = (u32)(ks[2 * t] & 0xFFFFu) | ((u32)(ks[2 * t + 1] & 0xFFFFu) << 16);
}

// ---------------------------------------------------------------- KNN merge
// One WAVE per query (32768 waves). Coalesced 512B read of the query's 256
// entries (4/lane), exact u64 keys recomputed (gathers pipelined), per-lane
// sort-4, then 16 rounds of wave-wide u64 min extraction (unique keys =>
// unique winner advances its sorted head). Ordering identical to the serial
// exact-key merge.
__global__ __launch_bounds__(256) void knn_merge(const float4* __restrict__ pts,
                                                 const unsigned short* __restrict__ part16,
                                                 int* __restrict__ idx16) {
    int wavein = threadIdx.x >> 6, lane = threadIdx.x & 63;
    int q = blockIdx.x * 4 + wavein;
    int b = q >> 13;
    float4 me = pts[q];
    ushort4 e = *(const ushort4*)(part16 + (size_t)q * 256 + lane * 4);
    u64 k0, k1, k2, k3;
    {
        u32 id;
        id = e.x; k0 = (id != 0xFFFFu) ? (((u64)fordkey(pdist(me, pts[b * NPTS + id])) << 32) | id) : ~0ull;
        id = e.y; k1 = (id != 0xFFFFu) ? (((u64)fordkey(pdist(me, pts[b * NPTS + id])) << 32) | id) : ~0ull;
        id = e.z; k2 = (id != 0xFFFFu) ? (((u64)fordkey(pdist(me, pts[b * NPTS + id])) << 32) | id) : ~0ull;
        id = e.w; k3 = (id != 0xFFFFu) ? (((u64)fordkey(pdist(me, pts[b * NPTS + id])) << 32) | id) : ~0ull;
    }
    // sort4 (network: (0,1)(2,3)(0,2)(1,3)(1,2))
    u64 t;
    if (k1 < k0) { t = k0; k0 = k1; k1 = t; }
    if (k3 < k2) { t = k2; k2 = k3; k3 = t; }
    if (k2 < k0) { t = k0; k0 = k2; k2 = t; }
    if (k3 < k1) { t = k1; k1 = k3; k3 = t; }
    if (k2 < k1) { t = k1; k1 = k2; k2 = t; }

    u64 cur = k0;
    int head = 0;
    u64 got = 0;
#pragma unroll
    for (int it = 0; it < 16; ++it) {
        u64 m = cur;
#pragma unroll
        for (int s = 32; s >= 1; s >>= 1) {
            u64 o = __shfl_xor(m, s);
            m = (o < m) ? o : m;
        }
        if (m == cur) {           // unique winner (idx embedded in key)
            head++;
            cur = (head == 1) ? k1 : (head == 2) ? k2 : (head == 3) ? k3 : ~0ull;
        }
        if (lane == it) got = m;
    }
    if (lane < 16) idx16[q * KNN + lane] = (int)(got & 0xFFFFFFFFu);
}

// ---------------------------------------------------------------- GEMM 32-row
// X fp32, W pre-packed bf16 pairs (global, staged to LDS), accum fp32.
// MODE 0: Vf   = X @ Wv + bv                      -> fp32
// MODE 1: T1   = X @ Wp2 + bp2 + add(vagg)        -> fp32
// MODE 2: out  = featb + gamma*(X @ Wo + bo)      -> fp32
template <int MODE>
__global__ __launch_bounds__(256) void gemm32(const float* __restrict__ X,
                                              const u32* __restrict__ Wb,
                                              const float* __restrict__ bias,
                                              const float* __restrict__ add,
                                              const float* __restrict__ featb,
                                              const float* __restrict__ gammap,
                                              float* __restrict__ outv) {
    __shared__ u32 Ws[DIM * DIM / 2];   // 32 KB packed bf16 pairs, [c][d/2]
    __shared__ float Xs[8 * DIM];       // 4 KB
    __shared__ float bs[DIM];
    int tid = threadIdx.x;
    {
        const uint4* src = (const uint4*)Wb;
        uint4* dst = (uint4*)Ws;
        for (int i = tid; i < DIM * DIM / 8; i += 256) dst[i] = src[i];
    }
    if (tid < 128) bs[tid] = bias[tid];
    float gamma = 0.f;
    if (MODE == 2) gamma = *gammap;

    int rowBase = blockIdx.x * 32;
    int d4 = (tid & 31) * 4;
    int row = tid >> 5;  // 0..7

    for (int it = 0; it < 4; ++it) {
        int r0 = rowBase + it * 8;
        __syncthreads();
        ((float4*)Xs)[tid] = ((const float4*)(X + (size_t)r0 * DIM))[tid];
        __syncthreads();

        float a0 = bs[d4], a1 = bs[d4 + 1], a2 = bs[d4 + 2], a3 = bs[d4 + 3];
        const float* xr = &Xs[row * DIM];
#pragma unroll 8
        for (int c = 0; c < DIM; ++c) {
            float x = xr[c];
            uint2 w = *(const uint2*)&Ws[c * (DIM / 2) + (d4 >> 1)];
            a0 = fmaf(x, __uint_as_float(w.x << 16), a0);
            a1 = fmaf(x, __uint_as_float(w.x & 0xFFFF0000u), a1);
            a2 = fmaf(x, __uint_as_float(w.y << 16), a2);
            a3 = fmaf(x, __uint_as_float(w.y & 0xFFFF0000u), a3);
        }
        size_t off = (size_t)(r0 + row) * DIM + d4;
        if (MODE == 1) {
            float4 ad = *(const float4*)(add + off);
            a0 += ad.x; a1 += ad.y; a2 += ad.z; a3 += ad.w;
        }
        if (MODE == 2) {
            float4 fb = *(const float4*)(featb + off);
            a0 = fmaf(gamma, a0, fb.x);
            a1 = fmaf(gamma, a1, fb.y);
            a2 = fmaf(gamma, a2, fb.z);
            a3 = fmaf(gamma, a3, fb.w);
        }
        *(float4*)(outv + off) = make_float4(a0, a1, a2, a3);
    }
}

// ---------------------------------------------------------------- stage C
__global__ __launch_bounds__(256) void stage_c(const float4* __restrict__ pts,
                                               const int* __restrict__ idx16,
                                               const float* __restrict__ sK,
                                               const float* __restrict__ w2,
                                               const float* __restrict__ Wp1,
                                               const float* __restrict__ bp1,
                                               const float* __restrict__ Vf,
                                               float* __restrict__ vagg,
                                               float* __restrict__ hbar) {
    __shared__ float hs[4][KNN * DIM];  // 32 KB
    int wavein = threadIdx.x >> 6;
    int lid = threadIdx.x & 63;
    int p = blockIdx.x * 4 + wavein;
    int b = p >> 13;
    float4 me = pts[p];

    float wx_lo = Wp1[lid],        wx_hi = Wp1[64 + lid];
    float wy_lo = Wp1[128 + lid],  wy_hi = Wp1[192 + lid];
    float wz_lo = Wp1[256 + lid],  wz_hi = Wp1[320 + lid];
    float bl    = bp1[lid],        bh    = bp1[64 + lid];
    float w2l   = w2[lid],         w2h   = w2[64 + lid];

    int myidx = idx16[p * KNN + (lid & 15)];
    float* h = hs[wavein];
    float sc = -INFINITY;

    for (int k = 0; k < KNN; ++k) {
        int j = __shfl(myidx, k);
        int g = b * NPTS + j;
        float4 nb = pts[g];
        float rx = me.x - nb.x, ry = me.y - nb.y, rz = me.z - nb.z;
        float h_lo = fmaxf(0.f, fmaf(rx, wx_lo, fmaf(ry, wy_lo, fmaf(rz, wz_lo, bl))));
        float h_hi = fmaxf(0.f, fmaf(rx, wx_hi, fmaf(ry, wy_hi, fmaf(rz, wz_hi, bh))));
        h[k * DIM + lid] = h_lo;
        h[k * DIM + 64 + lid] = h_hi;
        float s = fmaf(h_lo, w2l, h_hi * w2h);
#pragma unroll
        for (int m = 32; m >= 1; m >>= 1) s += __shfl_xor(s, m);
        float score = s - sK[g];
        if (lid == k) sc = score;
    }
    float mx = sc;
#pragma unroll
    for (int m = 8; m >= 1; m >>= 1) mx = fmaxf(mx, __shfl_xor(mx, m));
    float e = (lid < 16) ? __expf(sc - mx) : 0.f;
    float ssum = e;
#pragma unroll
    for (int m = 8; m >= 1; m >>= 1) ssum += __shfl_xor(ssum, m);
    float a = e / ssum;

    float acc_lo = 0.f, acc_hi = 0.f, hb_lo = 0.f, hb_hi = 0.f;
    for (int k = 0; k < KNN; ++k) {
        float ak = __shfl(a, k);
        int j = __shfl(myidx, k);
        size_t g = (size_t)(b * NPTS + j) * DIM;
        acc_lo = fmaf(ak, Vf[g + lid], acc_lo);
        acc_hi = fmaf(ak, Vf[g + 64 + lid], acc_hi);
        hb_lo = fmaf(ak, h[k * DIM + lid], hb_lo);
        hb_hi = fmaf(ak, h[k * DIM + 64 + lid], hb_hi);
    }
    size_t o = (size_t)p * DIM;
    vagg[o + lid] = acc_lo;
    vagg[o + 64 + lid] = acc_hi;
    hbar[o + lid] = hb_lo;
    hbar[o + 64 + lid] = hb_hi;
}

// ---------------------------------------------------------------- launcher
extern "C" void kernel_launch(void* const* d_in, const int* in_sizes, int n_in,
                              void* d_out, int out_size, void* d_ws, size_t ws_size,
                              hipStream_t stream) {
    const float* xyz   = (const float*)d_in[0];
    const float* feat  = (const float*)d_in[1];
    // d_in[2]=Wq, d_in[3]=bq, d_in[5]=bk: provably irrelevant (softmax shift-invariance)
    const float* Wk    = (const float*)d_in[4];
    const float* Wv    = (const float*)d_in[6];
    const float* bv    = (const float*)d_in[7];
    const float* Wp1   = (const float*)d_in[8];
    const float* bp1   = (const float*)d_in[9];
    const float* Wp2   = (const float*)d_in[10];
    const float* bp2   = (const float*)d_in[11];
    const float* Wo    = (const float*)d_in[12];
    const float* bo    = (const float*)d_in[13];
    const float* gamma = (const float*)d_in[14];
    float* out = (float*)d_out;

    char* ws = (char*)d_ws;
    const size_t KB = 1024, MB = 1024 * 1024;
    float*  wk    = (float*)(ws + 0);                // 512 B
    float*  w2    = (float*)(ws + 4 * KB);           // 512 B
    float4* pts   = (float4*)(ws + 16 * KB);         // 512 KB
    float*  sKv   = (float*)(ws + 544 * KB);         // 128 KB
    u32*    Wb    = (u32*)(ws + 688 * KB);           // 96 KB (Wv|Wp2|Wo bf16)
    float*  dlim  = (float*)(ws + 1 * MB);           // 1 MB (NSUB x NROWS)
    unsigned short* part16 = (unsigned short*)(ws + 5 * MB); // 16 MB, query-major, dead after merge
    float*  vagg  = (float*)(ws + 5 * MB);           // 16 MB, aliases dead part16
    float*  hbarp = (float*)(ws + 21 * MB);          // 16 MB
    int*    idx16 = (int*)(ws + 37 * MB);            // 2 MB
    float*  Vf    = (float*)(ws + 39 * MB);          // 16 MB, dead after stage_c
    float*  T1    = (float*)(ws + 39 * MB);          // aliases Vf  (total 55 MB)

    prep_weights<<<1, 256, 0, stream>>>(Wk, Wp2, wk, w2);
    conv_weights<<<96, 256, 0, stream>>>(Wv, Wp2, Wo, Wb);
    prep_points<<<NROWS / 4, 256, 0, stream>>>(xyz, feat, wk, pts, sKv);
    gemm32<0><<<1024, 256, 0, stream>>>(feat, Wb, bv, nullptr, nullptr, nullptr, Vf);
    knn_limpass<<<dim3(NROWS / 256, NSUB), 256, 0, stream>>>(pts, dlim);
    knn_partial<<<dim3(NROWS / 256, SPLITS), 256, 0, stream>>>(pts, dlim, part16);
    knn_merge<<<NROWS / 4, 256, 0, stream>>>(pts, part16, idx16);
    stage_c<<<NROWS / 4, 256, 0, stream>>>(pts, idx16, sKv, w2, Wp1, bp1, Vf, vagg, hbarp);
    gemm32<1><<<1024, 256, 0, stream>>>(hbarp, Wb + 8192, bp2, vagg, nullptr, nullptr, T1);
    gemm32<2><<<1024, 256, 0, stream>>>(T1, Wb + 16384, bo, nullptr, feat, gamma, out);
}